// Round 9
// baseline (791.737 us; speedup 1.0000x reference)
//
#include <hip/hip_runtime.h>
#include <hip/hip_fp16.h>
#include <cstdint>
#include <cstddef>

// x[512,4096] fp32 ; gate/up codes [11008,4096] i32 ; down codes [4096,11008] i32
// absmax blocks of 64 along K ; out [512,4096] fp32
//
// R12 = R11 + (a) GEMM dequant software-pipeline, (b) dense-read repack v3.
//  (a) R11 post-mortem: GEMM 212->135us after halving L2 A-traffic; now
//      chain-bound (Mfma 29/VALU 26/Occ 28 = grid-limited 2.69blk/CU).
//      Per-kt serial DEQ kk0 -> A -> MFMA chain broken by computing
//      DEQ kk0(kt+1) DURING MFMA kk1(kt) (static bqk0A/bqk0B alternation);
//      DEQ kk1(kt) already overlaps MFMA kk0(kt). Aging invariant kept:
//      next-kt DEQ follows a waitcnt that retired its codes; LOADCQ(kt+2)
//      is always the newest vmem.
//  (b) R11 repack was ~125us/pass (scattered 16-line load instrs). v3:
//      block = 64-row tile x 4-kb window; stage1 reads 1KB CONTIGUOUS per
//      wave-instr (64 lanes x int4 of one row), packs nibbles to ushort LDS
//      with XOR swizzle (c ^ ((row&7)<<2)) -> 2-way banks (free); stage2:
//      each output dword = ONE u32 LDS read (swizzle-verified conflict-free),
//      32B coalesced stores. absmax staged via small LDS. ~35-45us/pass.

using float4v = __attribute__((ext_vector_type(4))) float;
using half8   = __attribute__((ext_vector_type(8))) _Float16;

__constant__ float NF4TAB[16] = {
  -1.0f, -0.6961928009986877f, -0.5250730514526367f, -0.39491748809814453f,
  -0.28444138169288635f, -0.18477343022823334f, -0.09105003625154495f, 0.0f,
  0.07958029955625534f, 0.16093020141124725f, 0.24611230194568634f,
  0.33791524171829224f, 0.44070982933044434f, 0.5626170039176941f,
  0.7229568362236023f, 1.0f };

// Packed A layout (M=512 fixed): element (m,k) at
//   (((k>>5)*32 + (m>>4))*64 + ((k>>3)&3)*16 + (m&15))*8 + (k&7)
// -> frag (mb,kb): 64 lanes x 16B dense at (kb*32+mb)*512 + lane*8.

// ---------------------------------------------------------------------------
// repack v3: codes[Nrows][K] i32 (0..15) + amax[Nrows][Kb] f32 ->
//   pb[tile][kb][lane][32B], pam[tile][kb][64] f32   (tile = 64 rows)
// GEMM contract (same as R11): lane l (l15=l&15, hi=l>>4) 32B =
//   {dk(j0,kk0),dk(j0,kk1),dk(j1,kk0),dk(j1,kk1)},{dk(j2,..),dk(j3,..)}
//   dk(j,kk) = codes row tile*64+j*16+l15, k = kb*64+kk*32+hi*8..+7,
//   byte b = c(2b)|c(2b+1)<<4, k ascending.
// Block = (tile, win of 4 kb). Stage1: wave w rows w*16..+15, instr i reads
// row w*16+i: 64 lanes x int4 = 1KB contiguous; pack -> ushort; LDS word
// col c0=lane>>1 swizzled c0^((row&7)<<2). Stage2: thread (kbi=t>>6, l):
// 8 x u32 LDS reads (bank = hi | 4*((kbi*2+kk)^(l15&7)) -> 32 banks, 2-way).
__global__ __launch_bounds__(256) void repack_kernel(
    const int* __restrict__ codes, const float* __restrict__ amax,
    unsigned char* __restrict__ pb, float* __restrict__ pam,
    int K, int Kb, int KbW)
{
  __shared__ unsigned st[64 * 32];       // 8KB: [row][32 swizzled u32 cols]
  __shared__ float amst[64 * 5];         // [row][4 kbi] pad 5

  const int tid  = threadIdx.x;
  const int lane = tid & 63;
  const int w    = tid >> 6;

  const int tile = blockIdx.x / KbW;
  const int win  = blockIdx.x % KbW;

  // ---- stage 1: dense reads + pack + swizzled LDS write
  {
    const int* base = codes + (size_t)tile * 64 * K + (size_t)win * 256;
    const int c0 = lane >> 1;            // u32 col before swizzle
    const int hw = lane & 1;
    #pragma unroll
    for (int i = 0; i < 16; ++i) {
      const int row = w * 16 + i;
      const int4 c = *(const int4*)(base + (size_t)row * K + lane * 4);
      const unsigned short v =
        (unsigned short)((c.x | (c.y << 4)) | ((c.z | (c.w << 4)) << 8));
      const int W = row * 32 + (c0 ^ ((row & 7) << 2));
      ((unsigned short*)st)[W * 2 + hw] = v;
    }
    // absmax stage: thread t -> (row = t>>2, q = t&3)
    const int arow = tid >> 2, q = tid & 3;
    amst[arow * 5 + q] =
      amax[(size_t)(tile * 64 + arow) * Kb + win * 4 + q];
  }
  __syncthreads();

  // ---- stage 2: gather 8 dwords, 32B coalesced store
  {
    const int kbi = tid >> 6;            // 0..3
    const int l15 = lane & 15;
    const int hi  = lane >> 4;
    const int kb  = win * 4 + kbi;
    unsigned d[4][2];
    #pragma unroll
    for (int j = 0; j < 4; ++j) {
      const int row = j * 16 + l15;
      const int sw  = (row & 7) << 2;
      #pragma unroll
      for (int kk = 0; kk < 2; ++kk) {
        const int c = kbi * 8 + kk * 4 + hi;
        d[j][kk] = st[row * 32 + (c ^ sw)];
      }
    }
    uint4 o0, o1;
    o0.x = d[0][0]; o0.y = d[0][1]; o0.z = d[1][0]; o0.w = d[1][1];
    o1.x = d[2][0]; o1.y = d[2][1]; o1.z = d[3][0]; o1.w = d[3][1];
    uint4* dst = (uint4*)(pb + (((size_t)tile * Kb + kb) * 64 + lane) * 32);
    dst[0] = o0; dst[1] = o1;

    pam[((size_t)tile * Kb + kb) * 64 + lane] = amst[lane * 5 + kbi];
  }
}

// ---------------------------------------------------------------------------
// C[512 x N] = A_packed * dequant(packed codes)^T
// Block 256M x 64N, BK=64, 4 waves, wave tile 64x64 (4x4 MFMA 16x16x32 f16).
// ATOMIC=false: r2 selects gate/up matrix; C stored f16 PACKED.
// ATOMIC=true : r2 = K-chunk (split-K); fp32 atomicAdd into row-major outF.
template <bool ATOMIC>
__global__ __launch_bounds__(256, 3) void gemm_nf4(
    const __half* __restrict__ Apk,
    const unsigned char* __restrict__ p0, const float* __restrict__ am0,
    const unsigned char* __restrict__ p1, const float* __restrict__ am1,
    __half* __restrict__ o0, __half* __restrict__ o1,
    float* __restrict__ outF,
    int N, int K, int Kc, int Ntiles)
{
  __shared__ unsigned ptab[256];         // packed f16 pair {tab[lo],tab[hi]}

  const int tid  = threadIdx.x;
  const int lane = tid & 63;
  const int wave = tid >> 6;
  const int l15  = lane & 15;

  {
    __half2 pr = __floats2half2_rn(NF4TAB[tid & 15], NF4TAB[tid >> 4]);
    ptab[tid] = *(const unsigned*)&pr;
  }
  __syncthreads();                       // ptab visible; ONLY barrier.

  int nt, r2, mt;
  if (ATOMIC) {
    const int xcd  = blockIdx.x & 7;
    const int slot = blockIdx.x >> 3;            // 0..63
    r2 = xcd >> 1;                               // K-chunk 0..3
    mt = slot & 1;
    nt = (slot >> 1) + (xcd & 1) * 32;           // 0..63
  } else {
    const int nwg = gridDim.x;
    const int bid = (blockIdx.x & 7) * (nwg >> 3) + (blockIdx.x >> 3);
    mt = bid & 1;
    const int r = bid >> 1;
    nt = r % Ntiles;
    r2 = r / Ntiles;                             // matrix select
  }

  const int k0 = ATOMIC ? r2 * Kc : 0;
  const int nk = Kc >> 6;
  const unsigned char* pk = (!ATOMIC && r2) ? p1 : p0;
  const float* amx        = (!ATOMIC && r2) ? am1 : am0;
  __half* outH            = (!ATOMIC && r2) ? o1 : o0;

  const int col0 = nt * 64;
  const int Kb   = K >> 6;
  const int kb0q = k0 >> 6;

  const uint4* pc  = (const uint4*)(pk + (((size_t)nt * Kb + kb0q) * 64 + lane) * 32);
  const float* pam = amx + ((size_t)nt * Kb + kb0q) * 64 + l15;

  const int mb0 = mt * 16 + wave * 4;
  const __half* pA = Apk + ((size_t)((k0 >> 5) * 32 + mb0) * 512)
                         + (size_t)lane * 8;

  float4v acc[4][4];
  {
    float4v z = {0.f, 0.f, 0.f, 0.f};
    #pragma unroll
    for (int i = 0; i < 4; ++i)
      #pragma unroll
      for (int j = 0; j < 4; ++j) acc[i][j] = z;
  }

  // 2-deep code prefetch, STATIC slots; bqk0 double-buffer (static A/B).
  uint4 q0_0, q1_0, q0_1, q1_1;
  float af_0[4], af_1[4];
  half8 bqk0A[4], bqk0B[4];

#define LOADCQ0(KT)                                                             \
  { const uint4* _p = pc + (size_t)(KT) * 128;                                  \
    q0_0 = _p[0]; q1_0 = _p[1];                                                 \
    const float* _a = pam + (size_t)(KT) * 64;                                  \
    af_0[0] = _a[0]; af_0[1] = _a[16]; af_0[2] = _a[32]; af_0[3] = _a[48]; }
#define LOADCQ1(KT)                                                             \
  { const uint4* _p = pc + (size_t)(KT) * 128;                                  \
    q0_1 = _p[0]; q1_1 = _p[1];                                                 \
    const float* _a = pam + (size_t)(KT) * 64;                                  \
    af_1[0] = _a[0]; af_1[1] = _a[16]; af_1[2] = _a[32]; af_1[3] = _a[48]; }

#define DEQD(DST, D, AM2)                                                       \
  { unsigned _w0 = ptab[(D) & 255];                                             \
    unsigned _w1 = ptab[((D) >> 8) & 255];                                      \
    unsigned _w2 = ptab[((D) >> 16) & 255];                                     \
    unsigned _w3 = ptab[(D) >> 24];                                             \
    __half2 _p0 = __hmul2(*(const __half2*)&_w0, AM2);                          \
    __half2 _p1 = __hmul2(*(const __half2*)&_w1, AM2);                          \
    __half2 _p2 = __hmul2(*(const __half2*)&_w2, AM2);                          \
    __half2 _p3 = __hmul2(*(const __half2*)&_w3, AM2);                          \
    uint4 _wv;                                                                  \
    _wv.x = *(const unsigned*)&_p0; _wv.y = *(const unsigned*)&_p1;             \
    _wv.z = *(const unsigned*)&_p2; _wv.w = *(const unsigned*)&_p3;             \
    DST = *(const half8*)&_wv; }

// kk0 fragments (j0..j3) from slot S -> DST[0..3]
#define DEQ4_K0(DST, S)                                                         \
  { const __half _a0 = __float2half(af_##S[0]);                                 \
    const __half _a1 = __float2half(af_##S[1]);                                 \
    const __half _a2 = __float2half(af_##S[2]);                                 \
    const __half _a3 = __float2half(af_##S[3]);                                 \
    const __half2 _m0{_a0,_a0}, _m1{_a1,_a1}, _m2{_a2,_a2}, _m3{_a3,_a3};       \
    DEQD(DST[0], q0_##S.x, _m0); DEQD(DST[1], q0_##S.z, _m1);                   \
    DEQD(DST[2], q1_##S.x, _m2); DEQD(DST[3], q1_##S.z, _m3); }
#define DEQ4_K1(DST, S)                                                         \
  { const __half _a0 = __float2half(af_##S[0]);                                 \
    const __half _a1 = __float2half(af_##S[1]);                                 \
    const __half _a2 = __float2half(af_##S[2]);                                 \
    const __half _a3 = __float2half(af_##S[3]);                                 \
    const __half2 _m0{_a0,_a0}, _m1{_a1,_a1}, _m2{_a2,_a2}, _m3{_a3,_a3};       \
    DEQD(DST[0], q0_##S.y, _m0); DEQD(DST[1], q0_##S.w, _m1);                   \
    DEQD(DST[2], q1_##S.y, _m2); DEQD(DST[3], q1_##S.w, _m3); }

// BODY(KT): kk0 frags for KT pre-computed in CUR (prev body / prologue).
// Issue: A kk0 -> MFMA kk0 (waits A; codes for KT+1 already retired)
//   || DEQ kk1(KT) from slot S (overlaps MFMA kk0)
// -> A kk1 -> MFMA kk1 || DEQ kk0(KT+1) from slot SN into NXT
// -> LOADCQ_S(KT+2)  (newest vmem; never force-drained before aging)
#define BODY(KT, S, SN, CUR, NXT)                                               \
  { half8 ap[4], bqk1[4];                                                       \
    _Pragma("unroll")                                                           \
    for (int _i = 0; _i < 4; ++_i)                                              \
      ap[_i] = *(const half8*)(pA + (size_t)(KT) * 32768 + _i * 512);           \
    _Pragma("unroll")                                                           \
    for (int _i = 0; _i < 4; ++_i)                                              \
      _Pragma("unroll")                                                         \
      for (int _j = 0; _j < 4; ++_j)                                            \
        acc[_i][_j] = __builtin_amdgcn_mfma_f32_16x16x32_f16(ap[_i], CUR[_j], acc[_i][_j], 0, 0, 0); \
    DEQ4_K1(bqk1, S);                                                           \
    _Pragma("unroll")                                                           \
    for (int _i = 0; _i < 4; ++_i)                                              \
      ap[_i] = *(const half8*)(pA + (size_t)(KT) * 32768 + 16384 + _i * 512);   \
    _Pragma("unroll")                                                           \
    for (int _i = 0; _i < 4; ++_i)                                              \
      _Pragma("unroll")                                                         \
      for (int _j = 0; _j < 4; ++_j)                                            \
        acc[_i][_j] = __builtin_amdgcn_mfma_f32_16x16x32_f16(ap[_i], bqk1[_j], acc[_i][_j], 0, 0, 0); \
    if ((KT) + 1 < nk) { DEQ4_K0(NXT, SN); }                                    \
    if ((KT) + 2 < nk) { LOADCQ##S((KT) + 2); } }

  LOADCQ0(0);
  LOADCQ1(1);                    // nk >= 43 always
  DEQ4_K0(bqk0A, 0);             // kk0 frags for kt=0 (waits q0_0 naturally)

  int kt = 0;
  while (kt + 2 <= nk) {
    BODY(kt,     0, 1, bqk0A, bqk0B);
    BODY(kt + 1, 1, 0, bqk0B, bqk0A);
    kt += 2;
  }
  if (kt < nk) BODY(kt, 0, 1, bqk0A, bqk0B);   // odd-nk tail (down nk=43)

  // ---- epilogue. C/D map: col = lane&15 (n), row = (lane>>4)*4 + reg (m)
  if (ATOMIC) {
    const int ccol0 = col0 + l15;
    const int crow0 = mt * 256 + wave * 64 + ((lane >> 4) << 2);
    #pragma unroll
    for (int i = 0; i < 4; ++i)
      #pragma unroll
      for (int j = 0; j < 4; ++j)
        #pragma unroll
        for (int rr = 0; rr < 4; ++rr) {
          const size_t idx = (size_t)(crow0 + i * 16 + rr) * N + (ccol0 + j * 16);
          atomicAdd(&outF[idx], acc[i][j][rr]);
        }
  } else {
    // store C packed (m = token row, n = this GEMM's out col = down's K):
    //   (((n>>5)*32 + (m>>4))*64 + ((n>>3)&3)*16 + (m&15))*8 + (n&7)
    const int jj    = lane & 7;
    const int lb    = (lane >> 3) & 1;
    const int rbase = (lane >> 4) << 2;
    #pragma unroll
    for (int i = 0; i < 4; ++i) {
      const int mb = mb0 + i;
      #pragma unroll
      for (int j = 0; j < 4; ++j) {
        const int kb = nt * 2 + (j >> 1);
        const int lp = ((j & 1) * 2 + lb) * 16 + rbase;
        #pragma unroll
        for (int rr = 0; rr < 4; ++rr) {
          const size_t a = ((size_t)(kb * 32 + mb) * 64 + (lp + rr)) * 8 + jj;
          outH[a] = __float2half(acc[i][j][rr]);
        }
      }
    }
  }
#undef LOADCQ0
#undef LOADCQ1
#undef DEQD
#undef DEQ4_K0
#undef DEQ4_K1
#undef BODY
}

// x fp32 row-major [512][4096] -> packed f16 fragment layout.
__global__ void cast_pack_kernel(const float* __restrict__ x,
                                 __half* __restrict__ xp, int nGrp) {
  int pid = blockIdx.x * blockDim.x + threadIdx.x;   // one per 8 halfs
  if (pid >= nGrp) return;
  const int lane = pid & 63;
  const int grp  = pid >> 6;
  const int mb   = grp & 31;          // M=512 -> 32 m-tiles
  const int kb   = grp >> 5;
  const int m = mb * 16 + (lane & 15);
  const int k = kb * 32 + ((lane >> 4) << 3);
  const float4* src = (const float4*)(x + (size_t)m * 4096 + k);
  float4 v0 = src[0], v1 = src[1];
  __half2 h0 = __floats2half2_rn(v0.x, v0.y), h1 = __floats2half2_rn(v0.z, v0.w);
  __half2 h2 = __floats2half2_rn(v1.x, v1.y), h3 = __floats2half2_rn(v1.z, v1.w);
  uint4 o;
  o.x = *(const unsigned*)&h0; o.y = *(const unsigned*)&h1;
  o.z = *(const unsigned*)&h2; o.w = *(const unsigned*)&h3;
  ((uint4*)xp)[pid] = o;
}

// elementwise silu(g)*u — layout-agnostic (g,u share the packed layout).
__global__ void swiglu_kernel(const __half* __restrict__ g,
                              const __half* __restrict__ u,
                              __half* __restrict__ h, int n2) {
  int i = blockIdx.x * blockDim.x + threadIdx.x;
  if (i < n2) {
    float2 gf = __half22float2(((const __half2*)g)[i]);
    float2 uf = __half22float2(((const __half2*)u)[i]);
    float h0 = gf.x / (1.f + __expf(-gf.x)) * uf.x;
    float h1 = gf.y / (1.f + __expf(-gf.y)) * uf.y;
    ((__half2*)h)[i] = __floats2half2_rn(h0, h1);
  }
}

extern "C" void kernel_launch(void* const* d_in, const int* in_sizes, int n_in,
                              void* d_out, int out_size, void* d_ws, size_t ws_size,
                              hipStream_t stream)
{
  (void)in_sizes; (void)n_in; (void)ws_size;
  const float* x            = (const float*)d_in[0];
  const int*   gate_codes   = (const int*)d_in[1];
  const float* gate_absmax  = (const float*)d_in[2];
  const int*   up_codes     = (const int*)d_in[3];
  const float* up_absmax    = (const float*)d_in[4];
  const int*   down_codes   = (const int*)d_in[5];
  const float* down_absmax  = (const float*)d_in[6];
  float* out = (float*)d_out;

  // ws layout (bytes):
  //  xp 4.19MB | g 11.27MB | u 11.27MB |
  //  pg 22.5MB | pu 22.5MB | pd 22.5MB | amg 2.82MB | amu 2.82MB | amd 2.82MB
  __half* xp = (__half*)d_ws;
  __half* g  = xp + (size_t)512 * 4096;
  __half* u  = g  + (size_t)512 * 11008;
  unsigned char* pg = (unsigned char*)(u + (size_t)512 * 11008);
  unsigned char* pu = pg + (size_t)172 * 64 * 2048;   // 172 tiles x 64 kb x 2KB
  unsigned char* pd = pu + (size_t)172 * 64 * 2048;
  float* amg = (float*)(pd + (size_t)64 * 172 * 2048);
  float* amu = amg + (size_t)172 * 64 * 64;
  float* amd = amu + (size_t)172 * 64 * 64;

  hipMemsetAsync(d_out, 0, (size_t)out_size * sizeof(float), stream);

  cast_pack_kernel<<<1024, 256, 0, stream>>>(x, xp, (512 * 4096) / 8);

  // repack v3: gate/up 172 tiles x 16 wins = 2752 blocks; down 64 x 43 = 2752
  repack_kernel<<<2752, 256, 0, stream>>>(gate_codes, gate_absmax, pg, amg,
                                          4096, 64, 16);
  repack_kernel<<<2752, 256, 0, stream>>>(up_codes, up_absmax, pu, amu,
                                          4096, 64, 16);
  repack_kernel<<<2752, 256, 0, stream>>>(down_codes, down_absmax, pd, amd,
                                          11008, 172, 43);

  // fused gate+up: 2 Mt x 172 Nt x 2 mats = 688 blocks
  gemm_nf4<false><<<688, 256, 0, stream>>>(xp, pg, amg, pu, amu,
                                           g, u, nullptr,
                                           11008, 4096, 4096, 172);

  swiglu_kernel<<<11008, 256, 0, stream>>>(g, u, g, (512 * 11008) / 2);

  // down: out += h * Wd^T, split-K=4: 2 Mt x 64 Nt x 4 = 512 blocks
  gemm_nf4<true><<<512, 256, 0, stream>>>(g, pd, amd,
                                          nullptr, nullptr, nullptr, nullptr,
                                          out, 4096, 11008, 2752, 64);
}

// Round 10
// 701.726 us; speedup vs baseline: 1.1283x; 1.1283x over previous
//
#include <hip/hip_runtime.h>
#include <hip/hip_fp16.h>
#include <cstdint>
#include <cstddef>

// x[512,4096] fp32 ; gate/up codes [11008,4096] i32 ; down codes [4096,11008] i32
// absmax blocks of 64 along K ; out [512,4096] fp32
//
// R13 = revert GEMM to R11-exact + merged single-launch repack (cap experiment).
//  - R12 post-mortem: dequant-ahead pipeline REGRESSED gemms 135->188
//    (MfmaUtil 29->20, VGPR 76->84, +12MB spill-ish writes). Reverted.
//  - Session-wide observation: EVERY kernel streaming the code matrices
//    (R6-R9 gemms, R11 reg-repack, R12 LDS-repack) converges to
//    ~1.4-1.8 TB/s effective HBM read BW regardless of access pattern;
//    nothing in any round ever exceeded 1.82 TB/s. Hypothesis: achievable
//    HBM-read ceiling here is ~1.8 TB/s, making the composite floor
//    ~640-690us. R13 tests it: all 3 repack passes merged into ONE
//    8256-block launch (one tail, 3x concurrent streams) with all 16
//    row-loads batched into registers (16-deep MLP/thread). The merged
//    repack becomes the top dispatch -> next round reads its hbm_gbps
//    directly: ~1.8 => composite roofline; >=2.5 => keep iterating.

using float4v = __attribute__((ext_vector_type(4))) float;
using half8   = __attribute__((ext_vector_type(8))) _Float16;

__constant__ float NF4TAB[16] = {
  -1.0f, -0.6961928009986877f, -0.5250730514526367f, -0.39491748809814453f,
  -0.28444138169288635f, -0.18477343022823334f, -0.09105003625154495f, 0.0f,
  0.07958029955625534f, 0.16093020141124725f, 0.24611230194568634f,
  0.33791524171829224f, 0.44070982933044434f, 0.5626170039176941f,
  0.7229568362236023f, 1.0f };

// Packed A layout (M=512 fixed): element (m,k) at
//   (((k>>5)*32 + (m>>4))*64 + ((k>>3)&3)*16 + (m&15))*8 + (k&7)
// -> frag (mb,kb): 64 lanes x 16B dense at (kb*32+mb)*512 + lane*8.

// ---------------------------------------------------------------------------
// merged repack: 3 matrices in one launch.
//  blocks [0,2752): gate (K=4096,Kb=64,KbW=16)
//  blocks [2752,5504): up   (same dims)
//  blocks [5504,8256): down (K=11008,Kb=172,KbW=43)
// Per block (tile = 64 rows, win = 4 kb):
//  stage1: wave w, instr i reads row w*16+i, 64 lanes x int4 = 1KB contiguous;
//          ALL 16 loads batched into regs first (16-deep), then pack->ushort
//          into LDS with XOR swizzle (c0 ^ ((row&7)<<2)).
//  stage2: thread (kbi=tid>>6, lane): 8 u32 LDS reads (2-way banks = free),
//          2x16B coalesced store; absmax staged via small LDS.
// Output contract (GEMM): lane l 32B = {dk(j0,kk0),dk(j0,kk1),dk(j1,kk0),
//  dk(j1,kk1)},{dk(j2..),dk(j3..)}; dk(j,kk) = row tile*64+j*16+(l&15),
//  k = kb*64+kk*32+(l>>4)*8..+7, byte = c(2b)|c(2b+1)<<4.
__global__ __launch_bounds__(256) void repack_kernel(
    const int* __restrict__ cg, const float* __restrict__ ag,
    const int* __restrict__ cu, const float* __restrict__ au,
    const int* __restrict__ cd, const float* __restrict__ ad,
    unsigned char* __restrict__ pg, float* __restrict__ amg,
    unsigned char* __restrict__ pu, float* __restrict__ amu,
    unsigned char* __restrict__ pd, float* __restrict__ amd)
{
  __shared__ unsigned st[64 * 32];       // 8KB: [row][32 swizzled u32 cols]
  __shared__ float amst[64 * 5];         // [row][4 kbi] pad 5

  const int tid  = threadIdx.x;
  const int lane = tid & 63;
  const int w    = tid >> 6;

  const int bid = blockIdx.x;
  const int* codes; const float* amax;
  unsigned char* pb; float* pam;
  int K, Kb, KbW, rel;
  if (bid < 2752)      { codes = cg; amax = ag; pb = pg; pam = amg;
                         K = 4096;  Kb = 64;  KbW = 16; rel = bid; }
  else if (bid < 5504) { codes = cu; amax = au; pb = pu; pam = amu;
                         K = 4096;  Kb = 64;  KbW = 16; rel = bid - 2752; }
  else                 { codes = cd; amax = ad; pb = pd; pam = amd;
                         K = 11008; Kb = 172; KbW = 43; rel = bid - 5504; }
  const int tile = rel / KbW;
  const int win  = rel % KbW;

  // ---- stage 1: batched dense reads, then pack + swizzled LDS write
  {
    const int* base = codes + (size_t)tile * 64 * K + (size_t)win * 256;
    int4 c[16];
    #pragma unroll
    for (int i = 0; i < 16; ++i) {
      const int row = w * 16 + i;
      c[i] = *(const int4*)(base + (size_t)row * K + lane * 4);
    }
    const int c0 = lane >> 1;            // u32 col before swizzle
    const int hw = lane & 1;
    #pragma unroll
    for (int i = 0; i < 16; ++i) {
      const int row = w * 16 + i;
      const unsigned short v =
        (unsigned short)((c[i].x | (c[i].y << 4)) |
                         ((c[i].z | (c[i].w << 4)) << 8));
      const int W = row * 32 + (c0 ^ ((row & 7) << 2));
      ((unsigned short*)st)[W * 2 + hw] = v;
    }
    const int arow = tid >> 2, q = tid & 3;
    amst[arow * 5 + q] =
      amax[(size_t)(tile * 64 + arow) * Kb + win * 4 + q];
  }
  __syncthreads();

  // ---- stage 2: gather 8 dwords, 32B coalesced store
  {
    const int kbi = tid >> 6;            // 0..3
    const int l15 = lane & 15;
    const int hi  = lane >> 4;
    const int kb  = win * 4 + kbi;
    unsigned d[4][2];
    #pragma unroll
    for (int j = 0; j < 4; ++j) {
      const int row = j * 16 + l15;
      const int sw  = (row & 7) << 2;
      #pragma unroll
      for (int kk = 0; kk < 2; ++kk) {
        const int c = kbi * 8 + kk * 4 + hi;
        d[j][kk] = st[row * 32 + (c ^ sw)];
      }
    }
    uint4 o0, o1;
    o0.x = d[0][0]; o0.y = d[0][1]; o0.z = d[1][0]; o0.w = d[1][1];
    o1.x = d[2][0]; o1.y = d[2][1]; o1.z = d[3][0]; o1.w = d[3][1];
    uint4* dst = (uint4*)(pb + (((size_t)tile * Kb + kb) * 64 + lane) * 32);
    dst[0] = o0; dst[1] = o1;

    pam[((size_t)tile * Kb + kb) * 64 + lane] = amst[lane * 5 + kbi];
  }
}

// ---------------------------------------------------------------------------
// C[512 x N] = A_packed * dequant(packed codes)^T        (R11-exact)
// Block 256M x 64N, BK=64, 4 waves, wave tile 64x64 (4x4 MFMA 16x16x32 f16).
// ATOMIC=false: r2 selects gate/up matrix; C stored f16 PACKED.
// ATOMIC=true : r2 = K-chunk (split-K); fp32 atomicAdd into row-major outF.
template <bool ATOMIC>
__global__ __launch_bounds__(256, 3) void gemm_nf4(
    const __half* __restrict__ Apk,
    const unsigned char* __restrict__ p0, const float* __restrict__ am0,
    const unsigned char* __restrict__ p1, const float* __restrict__ am1,
    __half* __restrict__ o0, __half* __restrict__ o1,
    float* __restrict__ outF,
    int N, int K, int Kc, int Ntiles)
{
  __shared__ unsigned ptab[256];         // packed f16 pair {tab[lo],tab[hi]}

  const int tid  = threadIdx.x;
  const int lane = tid & 63;
  const int wave = tid >> 6;
  const int l15  = lane & 15;

  {
    __half2 pr = __floats2half2_rn(NF4TAB[tid & 15], NF4TAB[tid >> 4]);
    ptab[tid] = *(const unsigned*)&pr;
  }
  __syncthreads();                       // ptab visible; ONLY barrier.

  int nt, r2, mt;
  if (ATOMIC) {
    const int xcd  = blockIdx.x & 7;
    const int slot = blockIdx.x >> 3;            // 0..63
    r2 = xcd >> 1;                               // K-chunk 0..3
    mt = slot & 1;
    nt = (slot >> 1) + (xcd & 1) * 32;           // 0..63
  } else {
    const int nwg = gridDim.x;
    const int bid = (blockIdx.x & 7) * (nwg >> 3) + (blockIdx.x >> 3);
    mt = bid & 1;
    const int r = bid >> 1;
    nt = r % Ntiles;
    r2 = r / Ntiles;                             // matrix select
  }

  const int k0 = ATOMIC ? r2 * Kc : 0;
  const int nk = Kc >> 6;
  const unsigned char* pk = (!ATOMIC && r2) ? p1 : p0;
  const float* amx        = (!ATOMIC && r2) ? am1 : am0;
  __half* outH            = (!ATOMIC && r2) ? o1 : o0;

  const int col0 = nt * 64;
  const int Kb   = K >> 6;
  const int kb0q = k0 >> 6;

  const uint4* pc  = (const uint4*)(pk + (((size_t)nt * Kb + kb0q) * 64 + lane) * 32);
  const float* pam = amx + ((size_t)nt * Kb + kb0q) * 64 + l15;

  const int mb0 = mt * 16 + wave * 4;
  const __half* pA = Apk + ((size_t)((k0 >> 5) * 32 + mb0) * 512)
                         + (size_t)lane * 8;

  float4v acc[4][4];
  {
    float4v z = {0.f, 0.f, 0.f, 0.f};
    #pragma unroll
    for (int i = 0; i < 4; ++i)
      #pragma unroll
      for (int j = 0; j < 4; ++j) acc[i][j] = z;
  }

  // 2-deep code prefetch, STATIC slots (R4 lesson: no runtime slot index)
  uint4 q0_0, q1_0, q0_1, q1_1;
  float af_0[4], af_1[4];

#define LOADCQ0(KT)                                                             \
  { const uint4* _p = pc + (size_t)(KT) * 128;                                  \
    q0_0 = _p[0]; q1_0 = _p[1];                                                 \
    const float* _a = pam + (size_t)(KT) * 64;                                  \
    af_0[0] = _a[0]; af_0[1] = _a[16]; af_0[2] = _a[32]; af_0[3] = _a[48]; }
#define LOADCQ1(KT)                                                             \
  { const uint4* _p = pc + (size_t)(KT) * 128;                                  \
    q0_1 = _p[0]; q1_1 = _p[1];                                                 \
    const float* _a = pam + (size_t)(KT) * 64;                                  \
    af_1[0] = _a[0]; af_1[1] = _a[16]; af_1[2] = _a[32]; af_1[3] = _a[48]; }

// one dword (4 packed bytes) + absmax half2 -> one half8 B-fragment
#define DEQD(DST, D, AM2)                                                       \
  { unsigned _w0 = ptab[(D) & 255];                                             \
    unsigned _w1 = ptab[((D) >> 8) & 255];                                      \
    unsigned _w2 = ptab[((D) >> 16) & 255];                                     \
    unsigned _w3 = ptab[(D) >> 24];                                             \
    __half2 _p0 = __hmul2(*(const __half2*)&_w0, AM2);                          \
    __half2 _p1 = __hmul2(*(const __half2*)&_w1, AM2);                          \
    __half2 _p2 = __hmul2(*(const __half2*)&_w2, AM2);                          \
    __half2 _p3 = __hmul2(*(const __half2*)&_w3, AM2);                          \
    uint4 _wv;                                                                  \
    _wv.x = *(const unsigned*)&_p0; _wv.y = *(const unsigned*)&_p1;             \
    _wv.z = *(const unsigned*)&_p2; _wv.w = *(const unsigned*)&_p3;             \
    DST = *(const half8*)&_wv; }

// BODY: codes for KT in slot S regs (aged >= 1 full iter). Issue order:
// DEQ kk0 (VALU+LDS) -> A kk0 (L2) -> MFMA kk0 (vmcnt retires A kk0 and
// anything older - all aged) -> DEQ kk1 -> A kk1 -> MFMA kk1 -> code loads
// for KT+2 issued LAST (newest; never force-drained before aging).
#define BODY(KT, S)                                                             \
  { half8 bq[4], ap[4];                                                         \
    { const __half _a0 = __float2half(af_##S[0]);                               \
      const __half _a1 = __float2half(af_##S[1]);                               \
      const __half _a2 = __float2half(af_##S[2]);                               \
      const __half _a3 = __float2half(af_##S[3]);                               \
      const __half2 _m0{_a0,_a0}, _m1{_a1,_a1}, _m2{_a2,_a2}, _m3{_a3,_a3};     \
      DEQD(bq[0], q0_##S.x, _m0); DEQD(bq[1], q0_##S.z, _m1);                   \
      DEQD(bq[2], q1_##S.x, _m2); DEQD(bq[3], q1_##S.z, _m3);                   \
      _Pragma("unroll")                                                         \
      for (int _i = 0; _i < 4; ++_i)                                            \
        ap[_i] = *(const half8*)(pA + (size_t)(KT) * 32768 + _i * 512);         \
      _Pragma("unroll")                                                         \
      for (int _i = 0; _i < 4; ++_i)                                            \
        _Pragma("unroll")                                                       \
        for (int _j = 0; _j < 4; ++_j)                                          \
          acc[_i][_j] = __builtin_amdgcn_mfma_f32_16x16x32_f16(ap[_i], bq[_j], acc[_i][_j], 0, 0, 0); \
      DEQD(bq[0], q0_##S.y, _m0); DEQD(bq[1], q0_##S.w, _m1);                   \
      DEQD(bq[2], q1_##S.y, _m2); DEQD(bq[3], q1_##S.w, _m3);                   \
      _Pragma("unroll")                                                         \
      for (int _i = 0; _i < 4; ++_i)                                            \
        ap[_i] = *(const half8*)(pA + (size_t)(KT) * 32768 + 16384 + _i * 512); \
      _Pragma("unroll")                                                         \
      for (int _i = 0; _i < 4; ++_i)                                            \
        _Pragma("unroll")                                                       \
        for (int _j = 0; _j < 4; ++_j)                                          \
          acc[_i][_j] = __builtin_amdgcn_mfma_f32_16x16x32_f16(ap[_i], bq[_j], acc[_i][_j], 0, 0, 0); \
    }                                                                           \
    if ((KT) + 2 < nk) { LOADCQ##S((KT) + 2); } }

  LOADCQ0(0);
  if (nk > 1) LOADCQ1(1);

  int kt = 0;
  while (kt + 2 <= nk) { BODY(kt, 0); BODY(kt + 1, 1); kt += 2; }
  if (kt < nk) BODY(kt, 0);            // odd-nk tail (down: nk=43)

  // ---- epilogue. C/D map: col = lane&15 (n), row = (lane>>4)*4 + reg (m)
  if (ATOMIC) {
    const int ccol0 = col0 + l15;
    const int crow0 = mt * 256 + wave * 64 + ((lane >> 4) << 2);
    #pragma unroll
    for (int i = 0; i < 4; ++i)
      #pragma unroll
      for (int j = 0; j < 4; ++j)
        #pragma unroll
        for (int rr = 0; rr < 4; ++rr) {
          const size_t idx = (size_t)(crow0 + i * 16 + rr) * N + (ccol0 + j * 16);
          atomicAdd(&outF[idx], acc[i][j][rr]);
        }
  } else {
    // store C packed (m = token row, n = this GEMM's out col = down's K):
    //   (((n>>5)*32 + (m>>4))*64 + ((n>>3)&3)*16 + (m&15))*8 + (n&7)
    const int jj    = lane & 7;
    const int lb    = (lane >> 3) & 1;
    const int rbase = (lane >> 4) << 2;
    #pragma unroll
    for (int i = 0; i < 4; ++i) {
      const int mb = mb0 + i;
      #pragma unroll
      for (int j = 0; j < 4; ++j) {
        const int kb = nt * 2 + (j >> 1);
        const int lp = ((j & 1) * 2 + lb) * 16 + rbase;
        #pragma unroll
        for (int rr = 0; rr < 4; ++rr) {
          const size_t a = ((size_t)(kb * 32 + mb) * 64 + (lp + rr)) * 8 + jj;
          outH[a] = __float2half(acc[i][j][rr]);
        }
      }
    }
  }
#undef LOADCQ0
#undef LOADCQ1
#undef DEQD
#undef BODY
}

// x fp32 row-major [512][4096] -> packed f16 fragment layout.
__global__ void cast_pack_kernel(const float* __restrict__ x,
                                 __half* __restrict__ xp, int nGrp) {
  int pid = blockIdx.x * blockDim.x + threadIdx.x;   // one per 8 halfs
  if (pid >= nGrp) return;
  const int lane = pid & 63;
  const int grp  = pid >> 6;
  const int mb   = grp & 31;          // M=512 -> 32 m-tiles
  const int kb   = grp >> 5;
  const int m = mb * 16 + (lane & 15);
  const int k = kb * 32 + ((lane >> 4) << 3);
  const float4* src = (const float4*)(x + (size_t)m * 4096 + k);
  float4 v0 = src[0], v1 = src[1];
  __half2 h0 = __floats2half2_rn(v0.x, v0.y), h1 = __floats2half2_rn(v0.z, v0.w);
  __half2 h2 = __floats2half2_rn(v1.x, v1.y), h3 = __floats2half2_rn(v1.z, v1.w);
  uint4 o;
  o.x = *(const unsigned*)&h0; o.y = *(const unsigned*)&h1;
  o.z = *(const unsigned*)&h2; o.w = *(const unsigned*)&h3;
  ((uint4*)xp)[pid] = o;
}

// elementwise silu(g)*u — layout-agnostic (g,u share the packed layout).
__global__ void swiglu_kernel(const __half* __restrict__ g,
                              const __half* __restrict__ u,
                              __half* __restrict__ h, int n2) {
  int i = blockIdx.x * blockDim.x + threadIdx.x;
  if (i < n2) {
    float2 gf = __half22float2(((const __half2*)g)[i]);
    float2 uf = __half22float2(((const __half2*)u)[i]);
    float h0 = gf.x / (1.f + __expf(-gf.x)) * uf.x;
    float h1 = gf.y / (1.f + __expf(-gf.y)) * uf.y;
    ((__half2*)h)[i] = __floats2half2_rn(h0, h1);
  }
}

extern "C" void kernel_launch(void* const* d_in, const int* in_sizes, int n_in,
                              void* d_out, int out_size, void* d_ws, size_t ws_size,
                              hipStream_t stream)
{
  (void)in_sizes; (void)n_in; (void)ws_size;
  const float* x            = (const float*)d_in[0];
  const int*   gate_codes   = (const int*)d_in[1];
  const float* gate_absmax  = (const float*)d_in[2];
  const int*   up_codes     = (const int*)d_in[3];
  const float* up_absmax    = (const float*)d_in[4];
  const int*   down_codes   = (const int*)d_in[5];
  const float* down_absmax  = (const float*)d_in[6];
  float* out = (float*)d_out;

  // ws layout (bytes):
  //  xp 4.19MB | g 11.27MB | u 11.27MB |
  //  pg 22.5MB | pu 22.5MB | pd 22.5MB | amg 2.82MB | amu 2.82MB | amd 2.82MB
  __half* xp = (__half*)d_ws;
  __half* g  = xp + (size_t)512 * 4096;
  __half* u  = g  + (size_t)512 * 11008;
  unsigned char* pg = (unsigned char*)(u + (size_t)512 * 11008);
  unsigned char* pu = pg + (size_t)172 * 64 * 2048;   // 172 tiles x 64 kb x 2KB
  unsigned char* pd = pu + (size_t)172 * 64 * 2048;
  float* amg = (float*)(pd + (size_t)64 * 172 * 2048);
  float* amu = amg + (size_t)172 * 64 * 64;
  float* amd = amu + (size_t)172 * 64 * 64;

  hipMemsetAsync(d_out, 0, (size_t)out_size * sizeof(float), stream);

  cast_pack_kernel<<<1024, 256, 0, stream>>>(x, xp, (512 * 4096) / 8);

  // merged repack: gate [0,2752) + up [2752,5504) + down [5504,8256)
  repack_kernel<<<8256, 256, 0, stream>>>(gate_codes, gate_absmax,
                                          up_codes, up_absmax,
                                          down_codes, down_absmax,
                                          pg, amg, pu, amu, pd, amd);

  // fused gate+up: 2 Mt x 172 Nt x 2 mats = 688 blocks
  gemm_nf4<false><<<688, 256, 0, stream>>>(xp, pg, amg, pu, amu,
                                           g, u, nullptr,
                                           11008, 4096, 4096, 172);

  swiglu_kernel<<<11008, 256, 0, stream>>>(g, u, g, (512 * 11008) / 2);

  // down: out += h * Wd^T, split-K=4: 2 Mt x 64 Nt x 4 = 512 blocks
  gemm_nf4<true><<<512, 256, 0, stream>>>(g, pd, amd,
                                          nullptr, nullptr, nullptr, nullptr,
                                          out, 4096, 11008, 2752, 64);
}

// Round 12
// 693.327 us; speedup vs baseline: 1.1419x; 1.0121x over previous
//
#include <hip/hip_runtime.h>
#include <hip/hip_fp16.h>
#include <cstdint>
#include <cstddef>

// x[512,4096] fp32 ; gate/up codes [11008,4096] i32 ; down codes [4096,11008] i32
// absmax blocks of 64 along K ; out [512,4096] fp32
//
// R14 (resubmit — GPUAcquisitionTimeout, never ran):
// quarter the GEMM block's A-footprint: BM 256->128, BN 64->128.
//  - R13 post-mortem: merged repack measured directly: 168us @ 2.25TB/s
//    (broke the 1.8 cap; FETCH 297MB < 541 compulsory -> L3 absorbs 45%).
//    Repack near pattern-limited floor; GEMMs (~135 ea) are the bigger cost.
//  - Only lever that ever moved the GEMM: L2 A-traffic (R10->R11: halved
//    traffic = -36%). R14 halves it AGAIN with zero per-wave changes:
//    128x128 block = 2x2 waves of the SAME 64x64 wave tile (same acc[4][4],
//    same BODY macro, same 76 VGPR, same 256 thr, same 688/512 grids).
//    A L2-traffic: gate/up 1.37GB->688MB, down 720->360MB.
//  - mt-fast XCD chunking: 4 M-tiles of one (nt,mat) group share an XCD ->
//    code tiles L2-shared; A k-window stays small (lockstep walk).
//  - Repack byte-identical to R13 (control). R12's pipeline lesson: do NOT
//    touch BODY/dequant scheduling.

using float4v = __attribute__((ext_vector_type(4))) float;
using half8   = __attribute__((ext_vector_type(8))) _Float16;

__constant__ float NF4TAB[16] = {
  -1.0f, -0.6961928009986877f, -0.5250730514526367f, -0.39491748809814453f,
  -0.28444138169288635f, -0.18477343022823334f, -0.09105003625154495f, 0.0f,
  0.07958029955625534f, 0.16093020141124725f, 0.24611230194568634f,
  0.33791524171829224f, 0.44070982933044434f, 0.5626170039176941f,
  0.7229568362236023f, 1.0f };

// Packed A layout (M=512 fixed): element (m,k) at
//   (((k>>5)*32 + (m>>4))*64 + ((k>>3)&3)*16 + (m&15))*8 + (k&7)
// -> frag (mb,kb): 64 lanes x 16B dense at (kb*32+mb)*512 + lane*8.

// ---------------------------------------------------------------------------
// merged repack (R13-identical): 3 matrices in one launch.
//  blocks [0,2752): gate (K=4096,Kb=64,KbW=16)
//  blocks [2752,5504): up   (same dims)
//  blocks [5504,8256): down (K=11008,Kb=172,KbW=43)
__global__ __launch_bounds__(256) void repack_kernel(
    const int* __restrict__ cg, const float* __restrict__ ag,
    const int* __restrict__ cu, const float* __restrict__ au,
    const int* __restrict__ cd, const float* __restrict__ ad,
    unsigned char* __restrict__ pg, float* __restrict__ amg,
    unsigned char* __restrict__ pu, float* __restrict__ amu,
    unsigned char* __restrict__ pd, float* __restrict__ amd)
{
  __shared__ unsigned st[64 * 32];       // 8KB: [row][32 swizzled u32 cols]
  __shared__ float amst[64 * 5];         // [row][4 kbi] pad 5

  const int tid  = threadIdx.x;
  const int lane = tid & 63;
  const int w    = tid >> 6;

  const int bid = blockIdx.x;
  const int* codes; const float* amax;
  unsigned char* pb; float* pam;
  int K, Kb, KbW, rel;
  if (bid < 2752)      { codes = cg; amax = ag; pb = pg; pam = amg;
                         K = 4096;  Kb = 64;  KbW = 16; rel = bid; }
  else if (bid < 5504) { codes = cu; amax = au; pb = pu; pam = amu;
                         K = 4096;  Kb = 64;  KbW = 16; rel = bid - 2752; }
  else                 { codes = cd; amax = ad; pb = pd; pam = amd;
                         K = 11008; Kb = 172; KbW = 43; rel = bid - 5504; }
  const int tile = rel / KbW;
  const int win  = rel % KbW;

  // ---- stage 1: batched dense reads, then pack + swizzled LDS write
  {
    const int* base = codes + (size_t)tile * 64 * K + (size_t)win * 256;
    int4 c[16];
    #pragma unroll
    for (int i = 0; i < 16; ++i) {
      const int row = w * 16 + i;
      c[i] = *(const int4*)(base + (size_t)row * K + lane * 4);
    }
    const int c0 = lane >> 1;            // u32 col before swizzle
    const int hw = lane & 1;
    #pragma unroll
    for (int i = 0; i < 16; ++i) {
      const int row = w * 16 + i;
      const unsigned short v =
        (unsigned short)((c[i].x | (c[i].y << 4)) |
                         ((c[i].z | (c[i].w << 4)) << 8));
      const int W = row * 32 + (c0 ^ ((row & 7) << 2));
      ((unsigned short*)st)[W * 2 + hw] = v;
    }
    const int arow = tid >> 2, q = tid & 3;
    amst[arow * 5 + q] =
      amax[(size_t)(tile * 64 + arow) * Kb + win * 4 + q];
  }
  __syncthreads();

  // ---- stage 2: gather 8 dwords, 32B coalesced store
  {
    const int kbi = tid >> 6;            // 0..3
    const int l15 = lane & 15;
    const int hi  = lane >> 4;
    const int kb  = win * 4 + kbi;
    unsigned d[4][2];
    #pragma unroll
    for (int j = 0; j < 4; ++j) {
      const int row = j * 16 + l15;
      const int sw  = (row & 7) << 2;
      #pragma unroll
      for (int kk = 0; kk < 2; ++kk) {
        const int c = kbi * 8 + kk * 4 + hi;
        d[j][kk] = st[row * 32 + (c ^ sw)];
      }
    }
    uint4 o0, o1;
    o0.x = d[0][0]; o0.y = d[0][1]; o0.z = d[1][0]; o0.w = d[1][1];
    o1.x = d[2][0]; o1.y = d[2][1]; o1.z = d[3][0]; o1.w = d[3][1];
    uint4* dst = (uint4*)(pb + (((size_t)tile * Kb + kb) * 64 + lane) * 32);
    dst[0] = o0; dst[1] = o1;

    pam[((size_t)tile * Kb + kb) * 64 + lane] = amst[lane * 5 + kbi];
  }
}

// ---------------------------------------------------------------------------
// C[512 x N] = A_packed * dequant(packed codes)^T
// Block 128M x 128N, BK=64, 4 waves as 2x2 of 64x64 wave tiles
// (4x4 MFMA 16x16x32 f16 each — R11 BODY unchanged).
// ATOMIC=false: r2 selects gate/up matrix; C stored f16 PACKED.
// ATOMIC=true : r2 = K-chunk (split-K); fp32 atomicAdd into row-major outF.
template <bool ATOMIC>
__global__ __launch_bounds__(256, 3) void gemm_nf4(
    const __half* __restrict__ Apk,
    const unsigned char* __restrict__ p0, const float* __restrict__ am0,
    const unsigned char* __restrict__ p1, const float* __restrict__ am1,
    __half* __restrict__ o0, __half* __restrict__ o1,
    float* __restrict__ outF,
    int N, int K, int Kc, int Ntiles)
{
  __shared__ unsigned ptab[256];         // packed f16 pair {tab[lo],tab[hi]}

  const int tid  = threadIdx.x;
  const int lane = tid & 63;
  const int wave = tid >> 6;
  const int wm   = wave & 1;             // M wave row (0..1)
  const int wn   = wave >> 1;            // N wave col (0..1)
  const int l15  = lane & 15;

  {
    __half2 pr = __floats2half2_rn(NF4TAB[tid & 15], NF4TAB[tid >> 4]);
    ptab[tid] = *(const unsigned*)&pr;
  }
  __syncthreads();                       // ptab visible; ONLY barrier.

  int nt, r2, mt;
  if (ATOMIC) {
    const int xcd  = blockIdx.x & 7;
    const int slot = blockIdx.x >> 3;            // 0..63
    r2 = xcd >> 1;                               // K-chunk 0..3
    mt = slot & 3;                               // 4 M-tiles of 128
    nt = (slot >> 2) + (xcd & 1) * 16;           // 0..31 (128-col tiles)
  } else {
    const int nwg = gridDim.x;
    const int bid = (blockIdx.x & 7) * (nwg >> 3) + (blockIdx.x >> 3);
    mt = bid & 3;                                // mt fast: 4 Mtiles share XCD
    const int r = bid >> 2;
    nt = r % Ntiles;
    r2 = r / Ntiles;                             // matrix select
  }

  const int k0 = ATOMIC ? r2 * Kc : 0;
  const int nk = Kc >> 6;
  const unsigned char* pk = (!ATOMIC && r2) ? p1 : p0;
  const float* amx        = (!ATOMIC && r2) ? am1 : am0;
  __half* outH            = (!ATOMIC && r2) ? o1 : o0;

  const int col0 = nt * 128 + wn * 64;   // this wave's 64-col packed tile
  const int tl   = nt * 2 + wn;          // packed-tile index (64 rows each)
  const int Kb   = K >> 6;
  const int kb0q = k0 >> 6;

  const uint4* pc  = (const uint4*)(pk + (((size_t)tl * Kb + kb0q) * 64 + lane) * 32);
  const float* pam = amx + ((size_t)tl * Kb + kb0q) * 64 + l15;

  const int mb0 = mt * 8 + wm * 4;       // wave's 4 m-blocks (of 32)
  const __half* pA = Apk + ((size_t)((k0 >> 5) * 32 + mb0) * 512)
                         + (size_t)lane * 8;

  float4v acc[4][4];
  {
    float4v z = {0.f, 0.f, 0.f, 0.f};
    #pragma unroll
    for (int i = 0; i < 4; ++i)
      #pragma unroll
      for (int j = 0; j < 4; ++j) acc[i][j] = z;
  }

  // 2-deep code prefetch, STATIC slots (R4 lesson: no runtime slot index)
  uint4 q0_0, q1_0, q0_1, q1_1;
  float af_0[4], af_1[4];

#define LOADCQ0(KT)                                                             \
  { const uint4* _p = pc + (size_t)(KT) * 128;                                  \
    q0_0 = _p[0]; q1_0 = _p[1];                                                 \
    const float* _a = pam + (size_t)(KT) * 64;                                  \
    af_0[0] = _a[0]; af_0[1] = _a[16]; af_0[2] = _a[32]; af_0[3] = _a[48]; }
#define LOADCQ1(KT)                                                             \
  { const uint4* _p = pc + (size_t)(KT) * 128;                                  \
    q0_1 = _p[0]; q1_1 = _p[1];                                                 \
    const float* _a = pam + (size_t)(KT) * 64;                                  \
    af_1[0] = _a[0]; af_1[1] = _a[16]; af_1[2] = _a[32]; af_1[3] = _a[48]; }

// one dword (4 packed bytes) + absmax half2 -> one half8 B-fragment
#define DEQD(DST, D, AM2)                                                       \
  { unsigned _w0 = ptab[(D) & 255];                                             \
    unsigned _w1 = ptab[((D) >> 8) & 255];                                      \
    unsigned _w2 = ptab[((D) >> 16) & 255];                                     \
    unsigned _w3 = ptab[(D) >> 24];                                             \
    __half2 _p0 = __hmul2(*(const __half2*)&_w0, AM2);                          \
    __half2 _p1 = __hmul2(*(const __half2*)&_w1, AM2);                          \
    __half2 _p2 = __hmul2(*(const __half2*)&_w2, AM2);                          \
    __half2 _p3 = __hmul2(*(const __half2*)&_w3, AM2);                          \
    uint4 _wv;                                                                  \
    _wv.x = *(const unsigned*)&_p0; _wv.y = *(const unsigned*)&_p1;             \
    _wv.z = *(const unsigned*)&_p2; _wv.w = *(const unsigned*)&_p3;             \
    DST = *(const half8*)&_wv; }

// BODY: codes for KT in slot S regs (aged >= 1 full iter). Issue order:
// DEQ kk0 (VALU+LDS) -> A kk0 (L2) -> MFMA kk0 (vmcnt retires A kk0 and
// anything older - all aged) -> DEQ kk1 -> A kk1 -> MFMA kk1 -> code loads
// for KT+2 issued LAST (newest; never force-drained before aging).
#define BODY(KT, S)                                                             \
  { half8 bq[4], ap[4];                                                         \
    { const __half _a0 = __float2half(af_##S[0]);                               \
      const __half _a1 = __float2half(af_##S[1]);                               \
      const __half _a2 = __float2half(af_##S[2]);                               \
      const __half _a3 = __float2half(af_##S[3]);                               \
      const __half2 _m0{_a0,_a0}, _m1{_a1,_a1}, _m2{_a2,_a2}, _m3{_a3,_a3};     \
      DEQD(bq[0], q0_##S.x, _m0); DEQD(bq[1], q0_##S.z, _m1);                   \
      DEQD(bq[2], q1_##S.x, _m2); DEQD(bq[3], q1_##S.z, _m3);                   \
      _Pragma("unroll")                                                         \
      for (int _i = 0; _i < 4; ++_i)                                            \
        ap[_i] = *(const half8*)(pA + (size_t)(KT) * 32768 + _i * 512);         \
      _Pragma("unroll")                                                         \
      for (int _i = 0; _i < 4; ++_i)                                            \
        _Pragma("unroll")                                                       \
        for (int _j = 0; _j < 4; ++_j)                                          \
          acc[_i][_j] = __builtin_amdgcn_mfma_f32_16x16x32_f16(ap[_i], bq[_j], acc[_i][_j], 0, 0, 0); \
      DEQD(bq[0], q0_##S.y, _m0); DEQD(bq[1], q0_##S.w, _m1);                   \
      DEQD(bq[2], q1_##S.y, _m2); DEQD(bq[3], q1_##S.w, _m3);                   \
      _Pragma("unroll")                                                         \
      for (int _i = 0; _i < 4; ++_i)                                            \
        ap[_i] = *(const half8*)(pA + (size_t)(KT) * 32768 + 16384 + _i * 512); \
      _Pragma("unroll")                                                         \
      for (int _i = 0; _i < 4; ++_i)                                            \
        _Pragma("unroll")                                                       \
        for (int _j = 0; _j < 4; ++_j)                                          \
          acc[_i][_j] = __builtin_amdgcn_mfma_f32_16x16x32_f16(ap[_i], bq[_j], acc[_i][_j], 0, 0, 0); \
    }                                                                           \
    if ((KT) + 2 < nk) { LOADCQ##S((KT) + 2); } }

  LOADCQ0(0);
  if (nk > 1) LOADCQ1(1);

  int kt = 0;
  while (kt + 2 <= nk) { BODY(kt, 0); BODY(kt + 1, 1); kt += 2; }
  if (kt < nk) BODY(kt, 0);            // odd-nk tail (down: nk=43)

  // ---- epilogue. C/D map: col = lane&15 (n), row = (lane>>4)*4 + reg (m)
  if (ATOMIC) {
    const int ccol0 = col0 + l15;
    const int crow0 = mt * 128 + wm * 64 + ((lane >> 4) << 2);
    #pragma unroll
    for (int i = 0; i < 4; ++i)
      #pragma unroll
      for (int j = 0; j < 4; ++j)
        #pragma unroll
        for (int rr = 0; rr < 4; ++rr) {
          const size_t idx = (size_t)(crow0 + i * 16 + rr) * N + (ccol0 + j * 16);
          atomicAdd(&outF[idx], acc[i][j][rr]);
        }
  } else {
    // store C packed (m = token row, n = this GEMM's out col = down's K):
    //   (((n>>5)*32 + (m>>4))*64 + ((n>>3)&3)*16 + (m&15))*8 + (n&7)
    const int jj    = lane & 7;
    const int lb    = (lane >> 3) & 1;
    const int rbase = (lane >> 4) << 2;
    #pragma unroll
    for (int i = 0; i < 4; ++i) {
      const int mb = mb0 + i;
      #pragma unroll
      for (int j = 0; j < 4; ++j) {
        const int kb = nt * 4 + wn * 2 + (j >> 1);
        const int lp = ((j & 1) * 2 + lb) * 16 + rbase;
        #pragma unroll
        for (int rr = 0; rr < 4; ++rr) {
          const size_t a = ((size_t)(kb * 32 + mb) * 64 + (lp + rr)) * 8 + jj;
          outH[a] = __float2half(acc[i][j][rr]);
        }
      }
    }
  }
#undef LOADCQ0
#undef LOADCQ1
#undef DEQD
#undef BODY
}

// x fp32 row-major [512][4096] -> packed f16 fragment layout.
__global__ void cast_pack_kernel(const float* __restrict__ x,
                                 __half* __restrict__ xp, int nGrp) {
  int pid = blockIdx.x * blockDim.x + threadIdx.x;   // one per 8 halfs
  if (pid >= nGrp) return;
  const int lane = pid & 63;
  const int grp  = pid >> 6;
  const int mb   = grp & 31;          // M=512 -> 32 m-tiles
  const int kb   = grp >> 5;
  const int m = mb * 16 + (lane & 15);
  const int k = kb * 32 + ((lane >> 4) << 3);
  const float4* src = (const float4*)(x + (size_t)m * 4096 + k);
  float4 v0 = src[0], v1 = src[1];
  __half2 h0 = __floats2half2_rn(v0.x, v0.y), h1 = __floats2half2_rn(v0.z, v0.w);
  __half2 h2 = __floats2half2_rn(v1.x, v1.y), h3 = __floats2half2_rn(v1.z, v1.w);
  uint4 o;
  o.x = *(const unsigned*)&h0; o.y = *(const unsigned*)&h1;
  o.z = *(const unsigned*)&h2; o.w = *(const unsigned*)&h3;
  ((uint4*)xp)[pid] = o;
}

// elementwise silu(g)*u — layout-agnostic (g,u share the packed layout).
__global__ void swiglu_kernel(const __half* __restrict__ g,
                              const __half* __restrict__ u,
                              __half* __restrict__ h, int n2) {
  int i = blockIdx.x * blockDim.x + threadIdx.x;
  if (i < n2) {
    float2 gf = __half22float2(((const __half2*)g)[i]);
    float2 uf = __half22float2(((const __half2*)u)[i]);
    float h0 = gf.x / (1.f + __expf(-gf.x)) * uf.x;
    float h1 = gf.y / (1.f + __expf(-gf.y)) * uf.y;
    ((__half2*)h)[i] = __floats2half2_rn(h0, h1);
  }
}

extern "C" void kernel_launch(void* const* d_in, const int* in_sizes, int n_in,
                              void* d_out, int out_size, void* d_ws, size_t ws_size,
                              hipStream_t stream)
{
  (void)in_sizes; (void)n_in; (void)ws_size;
  const float* x            = (const float*)d_in[0];
  const int*   gate_codes   = (const int*)d_in[1];
  const float* gate_absmax  = (const float*)d_in[2];
  const int*   up_codes     = (const int*)d_in[3];
  const float* up_absmax    = (const float*)d_in[4];
  const int*   down_codes   = (const int*)d_in[5];
  const float* down_absmax  = (const float*)d_in[6];
  float* out = (float*)d_out;

  // ws layout (bytes):
  //  xp 4.19MB | g 11.27MB | u 11.27MB |
  //  pg 22.5MB | pu 22.5MB | pd 22.5MB | amg 2.82MB | amu 2.82MB | amd 2.82MB
  __half* xp = (__half*)d_ws;
  __half* g  = xp + (size_t)512 * 4096;
  __half* u  = g  + (size_t)512 * 11008;
  unsigned char* pg = (unsigned char*)(u + (size_t)512 * 11008);
  unsigned char* pu = pg + (size_t)172 * 64 * 2048;   // 172 tiles x 64 kb x 2KB
  unsigned char* pd = pu + (size_t)172 * 64 * 2048;
  float* amg = (float*)(pd + (size_t)64 * 172 * 2048);
  float* amu = amg + (size_t)172 * 64 * 64;
  float* amd = amu + (size_t)172 * 64 * 64;

  hipMemsetAsync(d_out, 0, (size_t)out_size * sizeof(float), stream);

  cast_pack_kernel<<<1024, 256, 0, stream>>>(x, xp, (512 * 4096) / 8);

  // merged repack: gate [0,2752) + up [2752,5504) + down [5504,8256)
  repack_kernel<<<8256, 256, 0, stream>>>(gate_codes, gate_absmax,
                                          up_codes, up_absmax,
                                          down_codes, down_absmax,
                                          pg, amg, pu, amu, pd, amd);

  // fused gate+up: 4 Mt x 86 Nt x 2 mats = 688 blocks (128x128 tiles)
  gemm_nf4<false><<<688, 256, 0, stream>>>(xp, pg, amg, pu, amu,
                                           g, u, nullptr,
                                           11008, 4096, 4096, 86);

  swiglu_kernel<<<11008, 256, 0, stream>>>(g, u, g, (512 * 11008) / 2);

  // down: out += h * Wd^T, split-K=4: 4 Mt x 32 Nt x 4 = 512 blocks
  gemm_nf4<true><<<512, 256, 0, stream>>>(g, pd, amd,
                                          nullptr, nullptr, nullptr, nullptr,
                                          out, 4096, 11008, 2752, 32);
}